// Round 1
// baseline (847.463 us; speedup 1.0000x reference)
//
#include <hip/hip_runtime.h>

#define HW 4096
#define NC 512
#define NK 64
#define NB 64

typedef unsigned short u16;
typedef float  float4v __attribute__((ext_vector_type(4)));
typedef short  short8  __attribute__((ext_vector_type(8)));

__device__ __forceinline__ u16 f2bf(float f){
  unsigned u = __builtin_bit_cast(unsigned, f);
  u += 0x7fffu + ((u >> 16) & 1u);           // RNE to bf16
  return (u16)(u >> 16);
}
__device__ __forceinline__ unsigned pk2(float a, float b){
  return (unsigned)f2bf(a) | ((unsigned)f2bf(b) << 16);
}

// ---------------------------------------------------------------------------
// K1: per-pixel invnorm + 1x1-conv logits (bf16 MFMA) + softmax over K
// grid (16, 64): blockIdx.x = 256-pixel tile, blockIdx.y = batch. 256 thr.
// ---------------------------------------------------------------------------
__global__ __launch_bounds__(256) void nv_k1(
    const float* __restrict__ x, const float* __restrict__ w,
    const float* __restrict__ bias, float* __restrict__ invnorm,
    u16* __restrict__ a_out, float* __restrict__ asum)
{
  __shared__ u16 w_sh[NK * 40];     // [k][c_local] pitch 40 u16 (80 B)
  __shared__ u16 x_sh[256 * 40];    // [pixel][c_local] pitch 40 u16
  __shared__ float bias_sh[NK];

  const int t    = threadIdx.x;
  const int b    = blockIdx.y;
  const int p0   = blockIdx.x * 256;
  const int wave = t >> 6, lane = t & 63, q = lane >> 4, l16 = lane & 15;

  if (t < NK) bias_sh[t] = bias[t];

  const float* xb = x + (size_t)b * NC * HW;
  float sumsq = 0.f;

  float4v acc[4][4];
  const float4v zf = {0.f, 0.f, 0.f, 0.f};
  #pragma unroll
  for (int i = 0; i < 4; ++i)
    #pragma unroll
    for (int j = 0; j < 4; ++j) acc[i][j] = zf;

  for (int step = 0; step < 16; ++step){
    const int c0 = step * 32;
    __syncthreads();
    { // stage W chunk [64 x 32] -> bf16
      const int m = t >> 2, cq = (t & 3) * 8;
      const float* wp = w + m * NC + c0 + cq;
      float4 w0 = *(const float4*)wp;
      float4 w1 = *(const float4*)(wp + 4);
      uint4 pk;
      pk.x = pk2(w0.x, w0.y); pk.y = pk2(w0.z, w0.w);
      pk.z = pk2(w1.x, w1.y); pk.w = pk2(w1.z, w1.w);
      *(uint4*)&w_sh[m * 40 + cq] = pk;
    }
    { // stage X chunk [32 ch x 256 px] -> [px][ch] bf16, fused sumsq
      const float* xp = xb + (size_t)c0 * HW + p0 + t;
      #pragma unroll
      for (int c8 = 0; c8 < 4; ++c8){
        float v0 = xp[(c8*8+0)*HW], v1 = xp[(c8*8+1)*HW];
        float v2 = xp[(c8*8+2)*HW], v3 = xp[(c8*8+3)*HW];
        float v4 = xp[(c8*8+4)*HW], v5 = xp[(c8*8+5)*HW];
        float v6 = xp[(c8*8+6)*HW], v7 = xp[(c8*8+7)*HW];
        sumsq += v0*v0 + v1*v1 + v2*v2 + v3*v3 + v4*v4 + v5*v5 + v6*v6 + v7*v7;
        uint4 pk;
        pk.x = pk2(v0, v1); pk.y = pk2(v2, v3);
        pk.z = pk2(v4, v5); pk.w = pk2(v6, v7);
        *(uint4*)&x_sh[t * 40 + c8 * 8] = pk;
      }
    }
    __syncthreads();
    short8 av[4], bv[4];
    #pragma unroll
    for (int ms = 0; ms < 4; ++ms)
      av[ms] = *(const short8*)&w_sh[(ms*16 + l16) * 40 + q*8];
    #pragma unroll
    for (int ns = 0; ns < 4; ++ns)
      bv[ns] = *(const short8*)&x_sh[(wave*64 + ns*16 + l16) * 40 + q*8];
    #pragma unroll
    for (int ms = 0; ms < 4; ++ms)
      #pragma unroll
      for (int ns = 0; ns < 4; ++ns)
        acc[ms][ns] = __builtin_amdgcn_mfma_f32_16x16x32_bf16(av[ms], bv[ns], acc[ms][ns], 0, 0, 0);
  }

  // invnorm for this thread's pixel
  float inv = 1.f / fmaxf(sqrtf(sumsq), 1e-12f);
  invnorm[(size_t)b * HW + p0 + t] = inv;

  // softmax over K=64 (the 64 m-values for pixel n live in 4 q-lanes)
  float inv_n[4];
  #pragma unroll
  for (int ns = 0; ns < 4; ++ns) inv_n[ns] = __shfl(inv, ns*16 + l16, 64);

  #pragma unroll
  for (int ns = 0; ns < 4; ++ns){
    float mx = -3.4e38f;
    #pragma unroll
    for (int ms = 0; ms < 4; ++ms)
      #pragma unroll
      for (int r = 0; r < 4; ++r){
        float lv = fmaf(acc[ms][ns][r], inv_n[ns], bias_sh[ms*16 + q*4 + r]);
        acc[ms][ns][r] = lv;
        mx = fmaxf(mx, lv);
      }
    mx = fmaxf(mx, __shfl_xor(mx, 16, 64));
    mx = fmaxf(mx, __shfl_xor(mx, 32, 64));
    float s = 0.f;
    #pragma unroll
    for (int ms = 0; ms < 4; ++ms)
      #pragma unroll
      for (int r = 0; r < 4; ++r){
        float e = __expf(acc[ms][ns][r] - mx);
        acc[ms][ns][r] = e;
        s += e;
      }
    s += __shfl_xor(s, 16, 64);
    s += __shfl_xor(s, 32, 64);
    float is = 1.f / s;
    #pragma unroll
    for (int ms = 0; ms < 4; ++ms)
      #pragma unroll
      for (int r = 0; r < 4; ++r) acc[ms][ns][r] *= is;
  }

  // write soft-assign (bf16), coalesced in pixel dim
  u16* ap = a_out + (size_t)b * NK * HW + p0 + wave * 64;
  #pragma unroll
  for (int ms = 0; ms < 4; ++ms)
    #pragma unroll
    for (int r = 0; r < 4; ++r){
      const int m = ms*16 + q*4 + r;
      #pragma unroll
      for (int ns = 0; ns < 4; ++ns)
        ap[(size_t)m * HW + ns*16 + l16] = f2bf(acc[ms][ns][r]);
    }

  // asum[k] partials (fp32): sum over this wave's 64 pixels, then atomic
  #pragma unroll
  for (int ms = 0; ms < 4; ++ms)
    #pragma unroll
    for (int r = 0; r < 4; ++r){
      const int m = ms*16 + q*4 + r;
      float s = acc[ms][0][r] + acc[ms][1][r] + acc[ms][2][r] + acc[ms][3][r];
      s += __shfl_xor(s, 1, 64); s += __shfl_xor(s, 2, 64);
      s += __shfl_xor(s, 4, 64); s += __shfl_xor(s, 8, 64);
      if (l16 == 0) atomicAdd(&asum[b * NK + m], s);
    }
}

// ---------------------------------------------------------------------------
// K2: vlad[b,k,c] = sum_i a[k,i]*xn_flat[i*512+c] - asum[k]*cent[k,c]
// grid (4, 64): blockIdx.x = 128-wide c tile, blockIdx.y = batch. 256 thr.
// invnorm index of flat element i*512+c is (i&7)*512 + c.
// ---------------------------------------------------------------------------
__global__ __launch_bounds__(256) void nv_k2(
    const float* __restrict__ x, const u16* __restrict__ a_buf,
    const float* __restrict__ invnorm, const float* __restrict__ asum,
    const float* __restrict__ cent, float* __restrict__ vlad)
{
  __shared__ u16 a_sh[NK * 40];       // [k][i_local] pitch 40 u16
  __shared__ u16 x_sh[32 * 132];      // [i_local][c_local] pitch 132 u16
  __shared__ float inv_sh[8 * 128];   // [i&7][c_local]
  __shared__ float asum_sh[NK];

  const int t    = threadIdx.x;
  const int b    = blockIdx.y;
  const int cc0  = blockIdx.x * 128;
  const int wave = t >> 6, lane = t & 63, q = lane >> 4, l16 = lane & 15;

  { // preload invnorm segments needed by this c-range
    const int r = t >> 5, ccl = (t & 31) * 4;
    *(float4*)&inv_sh[r * 128 + ccl] =
        *(const float4*)&invnorm[(size_t)b * HW + r * NC + cc0 + ccl];
  }
  if (t < NK) asum_sh[t] = asum[b * NK + t];
  __syncthreads();

  const int il = t >> 5, cc_off = (t & 31) * 4;
  const float4 iv = *(const float4*)&inv_sh[il * 128 + cc_off];

  const float* xb = x + (size_t)b * NC * HW;
  const u16*   ab = a_buf + (size_t)b * NK * HW;

  float4v acc[4][2];
  const float4v zf = {0.f, 0.f, 0.f, 0.f};
  #pragma unroll
  for (int i = 0; i < 4; ++i){ acc[i][0] = zf; acc[i][1] = zf; }

  for (int step = 0; step < 128; ++step){
    const int i0 = step * 32;
    __syncthreads();
    { // stage a tile [64 x 32] (already bf16, natural layout)
      const int k = t >> 2, iq = (t & 3) * 8;
      *(float4*)&a_sh[k * 40 + iq] = *(const float4*)&ab[(size_t)k * HW + i0 + iq];
    }
    #pragma unroll
    for (int rr = 0; rr < 4; ++rr){ // stage x chunk rows, apply invnorm, ->bf16
      const int i = i0 + il + rr * 8;      // i&7 == il for all rr
      const float* xp = xb + (size_t)i * NC + cc0 + cc_off;
      float4 xv = *(const float4*)xp;
      uint2 pk;
      pk.x = pk2(xv.x * iv.x, xv.y * iv.y);
      pk.y = pk2(xv.z * iv.z, xv.w * iv.w);
      *(uint2*)&x_sh[(il + rr * 8) * 132 + cc_off] = pk;
    }
    __syncthreads();
    short8 av[4];
    #pragma unroll
    for (int ms = 0; ms < 4; ++ms)
      av[ms] = *(const short8*)&a_sh[(ms*16 + l16) * 40 + q*8];
    #pragma unroll
    for (int ns = 0; ns < 2; ++ns){
      const int nn = wave * 32 + ns * 16 + l16;
      short8 bv;
      #pragma unroll
      for (int j = 0; j < 8; ++j)
        bv[j] = (short)x_sh[(q*8 + j) * 132 + nn];
      #pragma unroll
      for (int ms = 0; ms < 4; ++ms)
        acc[ms][ns] = __builtin_amdgcn_mfma_f32_16x16x32_bf16(av[ms], bv, acc[ms][ns], 0, 0, 0);
    }
  }

  #pragma unroll
  for (int ms = 0; ms < 4; ++ms)
    #pragma unroll
    for (int ns = 0; ns < 2; ++ns)
      #pragma unroll
      for (int r = 0; r < 4; ++r){
        const int m = ms*16 + q*4 + r;
        const int n = cc0 + wave*32 + ns*16 + l16;
        float v = acc[ms][ns][r] - asum_sh[m] * cent[m * NC + n];
        vlad[(size_t)(b * NK + m) * NC + n] = v;
      }
}

// ---------------------------------------------------------------------------
// K3: intra-normalize per (b,k) over c, then global L2 per b. 64 blocks.
// ---------------------------------------------------------------------------
__global__ __launch_bounds__(256) void nv_k3(
    const float* __restrict__ vlad, float* __restrict__ out)
{
  __shared__ float part[256];
  __shared__ float rinv[NK];
  __shared__ float gsh[NK];
  __shared__ float gscale;

  const int b = blockIdx.x, t = threadIdx.x;
  const float* vb = vlad + (size_t)b * NK * NC;

  const int k = t >> 2, seg = t & 3;
  const float* vr = vb + k * NC + seg * 128;
  float s = 0.f;
  #pragma unroll 8
  for (int j = 0; j < 32; ++j){
    float4 v = *(const float4*)&vr[j * 4];
    s += v.x*v.x + v.y*v.y + v.z*v.z + v.w*v.w;
  }
  part[t] = s;
  __syncthreads();
  if (t < NK){
    float rs = part[t*4] + part[t*4+1] + part[t*4+2] + part[t*4+3];
    float ri = 1.f / fmaxf(sqrtf(rs), 1e-12f);
    rinv[t] = ri;
    gsh[t]  = rs * ri * ri;   // sumsq of normalized row
  }
  __syncthreads();
  if (t == 0){
    float g = 0.f;
    for (int i = 0; i < NK; ++i) g += gsh[i];
    gscale = 1.f / fmaxf(sqrtf(g), 1e-12f);
  }
  __syncthreads();
  const float gv = gscale;
  float* ob = out + (size_t)b * NK * NC;
  for (int j = 0; j < 32; ++j){
    const int idx = j * 1024 + t * 4;
    float4 v = *(const float4*)&vb[idx];
    float sc = rinv[idx >> 9] * gv;
    float4 o; o.x = v.x*sc; o.y = v.y*sc; o.z = v.z*sc; o.w = v.w*sc;
    *(float4*)&ob[idx] = o;
  }
}

// ---------------------------------------------------------------------------
extern "C" void kernel_launch(void* const* d_in, const int* in_sizes, int n_in,
                              void* d_out, int out_size, void* d_ws, size_t ws_size,
                              hipStream_t stream)
{
  (void)in_sizes; (void)n_in; (void)out_size; (void)ws_size;
  const float* x    = (const float*)d_in[0];
  const float* w    = (const float*)d_in[1];
  const float* bias = (const float*)d_in[2];
  const float* cent = (const float*)d_in[3];
  float* out = (float*)d_out;

  char* ws = (char*)d_ws;
  float* invnorm = (float*)ws;                                   // 1 MiB
  u16*   a_buf   = (u16*)(ws + (1u << 20));                      // 32 MiB
  float* asum    = (float*)(ws + (1u << 20) + (32u << 20));      // 16 KiB (padded 64K)
  float* vlad    = (float*)(ws + (1u << 20) + (32u << 20) + 65536u); // 8 MiB

  hipMemsetAsync(asum, 0, NB * NK * sizeof(float), stream);
  hipLaunchKernelGGL(nv_k1, dim3(16, 64), dim3(256), 0, stream,
                     x, w, bias, invnorm, a_buf, asum);
  hipLaunchKernelGGL(nv_k2, dim3(4, 64), dim3(256), 0, stream,
                     x, a_buf, invnorm, asum, cent, vlad);
  hipLaunchKernelGGL(nv_k3, dim3(64), dim3(256), 0, stream, vlad, out);
}

// Round 2
// 836.128 us; speedup vs baseline: 1.0136x; 1.0136x over previous
//
#include <hip/hip_runtime.h>

#define HW 4096
#define NC 512
#define NK 64
#define NB 64

typedef unsigned short u16;
typedef float  float4v __attribute__((ext_vector_type(4)));
typedef short  short8  __attribute__((ext_vector_type(8)));

__device__ __forceinline__ u16 f2bf(float f){
  unsigned u = __builtin_bit_cast(unsigned, f);
  u += 0x7fffu + ((u >> 16) & 1u);           // RNE to bf16
  return (u16)(u >> 16);
}
__device__ __forceinline__ unsigned pk2(float a, float b){
  return (unsigned)f2bf(a) | ((unsigned)f2bf(b) << 16);
}

// ---------------------------------------------------------------------------
// K1: per-pixel invnorm + 1x1-conv logits (bf16 MFMA) + softmax over K
// grid (16, 64): blockIdx.x = 256-pixel tile, blockIdx.y = batch. 256 thr.
// ---------------------------------------------------------------------------
__global__ __launch_bounds__(256) void nv_k1(
    const float* __restrict__ x, const float* __restrict__ w,
    const float* __restrict__ bias, float* __restrict__ invnorm,
    u16* __restrict__ a_out, float* __restrict__ asum)
{
  __shared__ u16 w_sh[NK * 40];     // [k][c_local] pitch 40 u16 (80 B)
  __shared__ u16 x_sh[256 * 40];    // [pixel][c_local] pitch 40 u16
  __shared__ float bias_sh[NK];

  const int t    = threadIdx.x;
  const int b    = blockIdx.y;
  const int p0   = blockIdx.x * 256;
  const int wave = t >> 6, lane = t & 63, q = lane >> 4, l16 = lane & 15;

  if (t < NK) bias_sh[t] = bias[t];

  const float* xb = x + (size_t)b * NC * HW;
  float sumsq = 0.f;

  float4v acc[4][4];
  const float4v zf = {0.f, 0.f, 0.f, 0.f};
  #pragma unroll
  for (int i = 0; i < 4; ++i)
    #pragma unroll
    for (int j = 0; j < 4; ++j) acc[i][j] = zf;

  for (int step = 0; step < 16; ++step){
    const int c0 = step * 32;
    __syncthreads();
    { // stage W chunk [64 x 32] -> bf16
      const int m = t >> 2, cq = (t & 3) * 8;
      const float* wp = w + m * NC + c0 + cq;
      float4 w0 = *(const float4*)wp;
      float4 w1 = *(const float4*)(wp + 4);
      uint4 pk;
      pk.x = pk2(w0.x, w0.y); pk.y = pk2(w0.z, w0.w);
      pk.z = pk2(w1.x, w1.y); pk.w = pk2(w1.z, w1.w);
      *(uint4*)&w_sh[m * 40 + cq] = pk;
    }
    { // stage X chunk [32 ch x 256 px] -> [px][ch] bf16, fused sumsq
      const float* xp = xb + (size_t)c0 * HW + p0 + t;
      #pragma unroll
      for (int c8 = 0; c8 < 4; ++c8){
        float v0 = xp[(c8*8+0)*HW], v1 = xp[(c8*8+1)*HW];
        float v2 = xp[(c8*8+2)*HW], v3 = xp[(c8*8+3)*HW];
        float v4 = xp[(c8*8+4)*HW], v5 = xp[(c8*8+5)*HW];
        float v6 = xp[(c8*8+6)*HW], v7 = xp[(c8*8+7)*HW];
        sumsq += v0*v0 + v1*v1 + v2*v2 + v3*v3 + v4*v4 + v5*v5 + v6*v6 + v7*v7;
        uint4 pk;
        pk.x = pk2(v0, v1); pk.y = pk2(v2, v3);
        pk.z = pk2(v4, v5); pk.w = pk2(v6, v7);
        *(uint4*)&x_sh[t * 40 + c8 * 8] = pk;
      }
    }
    __syncthreads();
    short8 av[4], bv[4];
    #pragma unroll
    for (int ms = 0; ms < 4; ++ms)
      av[ms] = *(const short8*)&w_sh[(ms*16 + l16) * 40 + q*8];
    #pragma unroll
    for (int ns = 0; ns < 4; ++ns)
      bv[ns] = *(const short8*)&x_sh[(wave*64 + ns*16 + l16) * 40 + q*8];
    #pragma unroll
    for (int ms = 0; ms < 4; ++ms)
      #pragma unroll
      for (int ns = 0; ns < 4; ++ns)
        acc[ms][ns] = __builtin_amdgcn_mfma_f32_16x16x32_bf16(av[ms], bv[ns], acc[ms][ns], 0, 0, 0);
  }

  // invnorm for this thread's pixel
  float inv = 1.f / fmaxf(sqrtf(sumsq), 1e-12f);
  invnorm[(size_t)b * HW + p0 + t] = inv;

  // softmax over K=64 (the 64 m-values for pixel n live in 4 q-lanes)
  float inv_n[4];
  #pragma unroll
  for (int ns = 0; ns < 4; ++ns) inv_n[ns] = __shfl(inv, ns*16 + l16, 64);

  #pragma unroll
  for (int ns = 0; ns < 4; ++ns){
    float mx = -3.4e38f;
    #pragma unroll
    for (int ms = 0; ms < 4; ++ms)
      #pragma unroll
      for (int r = 0; r < 4; ++r){
        float lv = fmaf(acc[ms][ns][r], inv_n[ns], bias_sh[ms*16 + q*4 + r]);
        acc[ms][ns][r] = lv;
        mx = fmaxf(mx, lv);
      }
    mx = fmaxf(mx, __shfl_xor(mx, 16, 64));
    mx = fmaxf(mx, __shfl_xor(mx, 32, 64));
    float s = 0.f;
    #pragma unroll
    for (int ms = 0; ms < 4; ++ms)
      #pragma unroll
      for (int r = 0; r < 4; ++r){
        float e = __expf(acc[ms][ns][r] - mx);
        acc[ms][ns][r] = e;
        s += e;
      }
    s += __shfl_xor(s, 16, 64);
    s += __shfl_xor(s, 32, 64);
    float is = 1.f / s;
    #pragma unroll
    for (int ms = 0; ms < 4; ++ms)
      #pragma unroll
      for (int r = 0; r < 4; ++r) acc[ms][ns][r] *= is;
  }

  // write soft-assign (bf16), coalesced in pixel dim
  u16* ap = a_out + (size_t)b * NK * HW + p0 + wave * 64;
  #pragma unroll
  for (int ms = 0; ms < 4; ++ms)
    #pragma unroll
    for (int r = 0; r < 4; ++r){
      const int m = ms*16 + q*4 + r;
      #pragma unroll
      for (int ns = 0; ns < 4; ++ns)
        ap[(size_t)m * HW + ns*16 + l16] = f2bf(acc[ms][ns][r]);
    }

  // asum[k] partials (fp32): sum over this wave's 64 pixels, then atomic
  #pragma unroll
  for (int ms = 0; ms < 4; ++ms)
    #pragma unroll
    for (int r = 0; r < 4; ++r){
      const int m = ms*16 + q*4 + r;
      float s = acc[ms][0][r] + acc[ms][1][r] + acc[ms][2][r] + acc[ms][3][r];
      s += __shfl_xor(s, 1, 64); s += __shfl_xor(s, 2, 64);
      s += __shfl_xor(s, 4, 64); s += __shfl_xor(s, 8, 64);
      if (l16 == 0) atomicAdd(&asum[b * NK + m], s);
    }
}

// ---------------------------------------------------------------------------
// K2: data term of vlad: part[iq][b,k,c] = sum_{i in quarter} a[k,i]*xf[i,c]
// xf[i,c] = x_flat[i*512+c]*invnorm[(i&7)*512+c] = x[ch=i>>3][p=j*512+c]*inv
// B-fragment needs 8 consecutive i per (c): those are x[ch][j*512+c], j=0..7
// -> direct coalesced global loads, NO x LDS staging / transpose.
// grid (2 c-tiles x 4 i-quarters x 64 b) = 512 blocks, 256 thr.
// ---------------------------------------------------------------------------
__global__ __launch_bounds__(256) void nv_k2(
    const float* __restrict__ x, const u16* __restrict__ a_buf,
    const float* __restrict__ invnorm, float* __restrict__ vpart)
{
  __shared__ u16 a_sh[NK * 40];       // [k][i_local] pitch 40 u16

  const int t    = threadIdx.x;
  const int b    = blockIdx.z;
  const int iq   = blockIdx.y;            // i in [iq*1024, iq*1024+1024)
  const int cc0  = blockIdx.x * 256;      // c-tile of 256
  const int wave = t >> 6, lane = t & 63, q = lane >> 4, l16 = lane & 15;

  const int cbase = cc0 + wave * 64 + l16;   // this lane's base column

  // invnorm is step-invariant per lane: invr[ns][j] = invnorm[j*512 + c(ns)]
  const float* invb = invnorm + (size_t)b * HW;
  float invr[4][8];
  #pragma unroll
  for (int ns = 0; ns < 4; ++ns)
    #pragma unroll
    for (int j = 0; j < 8; ++j)
      invr[ns][j] = invb[j * 512 + cbase + ns * 16];

  const float* xb  = x + (size_t)b * NC * HW;
  const u16*   ab  = a_buf + (size_t)b * NK * HW + iq * 1024;
  const float* xpb = xb + (size_t)(iq * 128 + q) * HW + cbase;  // ch = iq*128+q

  float4v acc[4][4];
  const float4v zf = {0.f, 0.f, 0.f, 0.f};
  #pragma unroll
  for (int i = 0; i < 4; ++i)
    #pragma unroll
    for (int j = 0; j < 4; ++j) acc[i][j] = zf;

  for (int step = 0; step < 32; ++step){
    const int i0 = step * 32;
    __syncthreads();
    { // stage a tile [64 k x 32 i] (bf16, natural layout)
      const int k = t >> 2, i8 = (t & 3) * 8;
      *(float4*)&a_sh[k * 40 + i8] = *(const float4*)&ab[(size_t)k * HW + i0 + i8];
    }
    __syncthreads();
    short8 av[4];
    #pragma unroll
    for (int ms = 0; ms < 4; ++ms)
      av[ms] = *(const short8*)&a_sh[(ms*16 + l16) * 40 + q*8];

    const float* xs = xpb + (size_t)step * 4 * HW;   // ch advances 4 per step
    #pragma unroll
    for (int ns = 0; ns < 4; ++ns){
      float v[8];
      #pragma unroll
      for (int j = 0; j < 8; ++j)
        v[j] = xs[j * 512 + ns * 16] * invr[ns][j];
      short8 bv;
      #pragma unroll
      for (int j = 0; j < 4; ++j)
        ((unsigned*)&bv)[j] = pk2(v[2*j], v[2*j+1]);
      #pragma unroll
      for (int ms = 0; ms < 4; ++ms)
        acc[ms][ns] = __builtin_amdgcn_mfma_f32_16x16x32_bf16(av[ms], bv, acc[ms][ns], 0, 0, 0);
    }
  }

  float* vp = vpart + (size_t)(iq * NB + b) * NK * NC;
  #pragma unroll
  for (int ms = 0; ms < 4; ++ms)
    #pragma unroll
    for (int ns = 0; ns < 4; ++ns)
      #pragma unroll
      for (int r = 0; r < 4; ++r){
        const int m = ms*16 + q*4 + r;
        const int n = cc0 + wave*64 + ns*16 + l16;
        vp[(size_t)m * NC + n] = acc[ms][ns][r];
      }
}

// ---------------------------------------------------------------------------
// K3a: vlad = sum_iq part[iq] - asum*cent; per-(b,k) row sumsq -> rstat.
// grid 64 (one per batch), 256 thr. rstat[b][0..63]=rinv, [64..127]=s_k
// ---------------------------------------------------------------------------
__global__ __launch_bounds__(256) void nv_k3a(
    const float* __restrict__ vpart, const float* __restrict__ asum,
    const float* __restrict__ cent, float* __restrict__ vlad,
    float* __restrict__ rstat)
{
  __shared__ float part_sh[256];
  const int b = blockIdx.x, t = threadIdx.x;
  const int k = t >> 2, seg = t & 3;
  const size_t roff = ((size_t)b * NK + k) * NC + seg * 128;
  const size_t bstride = (size_t)NB * NK * NC;
  const float* p0 = vpart + roff;
  const float as = asum[b * NK + k];
  const float* cp = cent + k * NC + seg * 128;
  float* vp = vlad + roff;

  float s = 0.f;
  #pragma unroll 4
  for (int j = 0; j < 32; ++j){
    float4 a0 = *(const float4*)&p0[j*4];
    float4 a1 = *(const float4*)&p0[bstride + j*4];
    float4 a2 = *(const float4*)&p0[2*bstride + j*4];
    float4 a3 = *(const float4*)&p0[3*bstride + j*4];
    float4 c4 = *(const float4*)&cp[j*4];
    float4 v;
    v.x = (a0.x + a1.x) + (a2.x + a3.x) - as * c4.x;
    v.y = (a0.y + a1.y) + (a2.y + a3.y) - as * c4.y;
    v.z = (a0.z + a1.z) + (a2.z + a3.z) - as * c4.z;
    v.w = (a0.w + a1.w) + (a2.w + a3.w) - as * c4.w;
    *(float4*)&vp[j*4] = v;
    s += v.x*v.x + v.y*v.y + v.z*v.z + v.w*v.w;
  }
  part_sh[t] = s;
  __syncthreads();
  if (t < NK){
    float rs = part_sh[t*4] + part_sh[t*4+1] + part_sh[t*4+2] + part_sh[t*4+3];
    float ri = 1.f / fmaxf(sqrtf(rs), 1e-12f);
    rstat[b * 128 + t]      = ri;
    rstat[b * 128 + 64 + t] = rs * ri * ri;  // sumsq of normalized row
  }
}

// ---------------------------------------------------------------------------
// K3c: out = vlad * rinv[k] * gscale(b). grid 64, 256 thr.
// ---------------------------------------------------------------------------
__global__ __launch_bounds__(256) void nv_k3c(
    const float* __restrict__ vlad, const float* __restrict__ rstat,
    float* __restrict__ out)
{
  __shared__ float rinv_sh[NK];
  __shared__ float gsh;
  const int b = blockIdx.x, t = threadIdx.x;
  if (t < 64){  // wave 0
    float ri = rstat[b * 128 + t];
    rinv_sh[t] = ri;
    float sk = rstat[b * 128 + 64 + t];
    sk += __shfl_xor(sk, 1, 64);  sk += __shfl_xor(sk, 2, 64);
    sk += __shfl_xor(sk, 4, 64);  sk += __shfl_xor(sk, 8, 64);
    sk += __shfl_xor(sk, 16, 64); sk += __shfl_xor(sk, 32, 64);
    if (t == 0) gsh = 1.f / fmaxf(sqrtf(sk), 1e-12f);
  }
  __syncthreads();
  const float g = gsh;
  const float* vb = vlad + (size_t)b * NK * NC;
  float* ob = out + (size_t)b * NK * NC;
  #pragma unroll 4
  for (int j = 0; j < 32; ++j){
    const int idx = j * 1024 + t * 4;
    float4 v = *(const float4*)&vb[idx];
    float sc = rinv_sh[idx >> 9] * g;
    float4 o; o.x = v.x*sc; o.y = v.y*sc; o.z = v.z*sc; o.w = v.w*sc;
    *(float4*)&ob[idx] = o;
  }
}

// ---------------------------------------------------------------------------
extern "C" void kernel_launch(void* const* d_in, const int* in_sizes, int n_in,
                              void* d_out, int out_size, void* d_ws, size_t ws_size,
                              hipStream_t stream)
{
  (void)in_sizes; (void)n_in; (void)out_size; (void)ws_size;
  const float* x    = (const float*)d_in[0];
  const float* w    = (const float*)d_in[1];
  const float* bias = (const float*)d_in[2];
  const float* cent = (const float*)d_in[3];
  float* out = (float*)d_out;

  char* ws = (char*)d_ws;
  float* invnorm = (float*)ws;                              // 1 MiB
  u16*   a_buf   = (u16*)(ws + (1u  << 20));                // 32 MiB
  float* asum    = (float*)(ws + (33u << 20));              // 16 KiB
  float* rstat   = (float*)(ws + (33u << 20) + 65536u);     // 32 KiB
  float* vlad    = (float*)(ws + (34u << 20));              // 8 MiB
  float* vpart   = (float*)(ws + (42u << 20));              // 32 MiB

  hipMemsetAsync(asum, 0, NB * NK * sizeof(float), stream);
  hipLaunchKernelGGL(nv_k1, dim3(16, 64), dim3(256), 0, stream,
                     x, w, bias, invnorm, a_buf, asum);
  hipLaunchKernelGGL(nv_k2, dim3(2, 4, 64), dim3(256), 0, stream,
                     x, a_buf, invnorm, vpart);
  hipLaunchKernelGGL(nv_k3a, dim3(64), dim3(256), 0, stream,
                     vpart, asum, cent, vlad, rstat);
  hipLaunchKernelGGL(nv_k3c, dim3(64), dim3(256), 0, stream,
                     vlad, rstat, out);
}